// Round 3
// baseline (35.076 us; speedup 1.0000x reference)
//
#include <hip/hip_runtime.h>

#define BATCH 128
#define DIM 256
#define NTH 6
#define NF 1536          // NUM_FACTS
#define NODES 1023
#define NPAD 1024
#define OD 8
#define INV_TAU (1.0f/0.7f)
#define CLIP_EPS 1e-6f

// tiling
#define BN2 32           // nodes per workgroup
#define KC2 96           // k-chunk per workgroup
#define KSPLIT 16        // 16 * 96 = 1536
#define GPITCH 104       // LDS g pitch (104%32==8 -> 2-way bank alias = free)
#define FPITCH 128       // LDS fact pitch (contiguous reads, conflict-free)

// ws layout (bytes)
#define OFF_PART 0            // partial [KSPLIT][BATCH][NPAD] f32 = 8388608
#define OFF_CS   8388608      // cS [KSPLIT][2][NPAD] f32 = 131072

__global__ __launch_bounds__(256) void k_fused(const float* __restrict__ x,
                                               const float* __restrict__ th,
                                               const float* __restrict__ sl,
                                               const float* __restrict__ logits,
                                               float* __restrict__ partial,
                                               float* __restrict__ cS) {
    __shared__ float fs[KC2 * FPITCH];   // 48 KiB: facts f[k][b] for this k-chunk
    __shared__ float gs[BN2 * GPITCH];   // 13 KiB: g = e1-e2 for this node tile
    const int tid = threadIdx.x;
    const int tile = blockIdx.x >> 4;       // 0..31
    const int chunk = blockIdx.x & 15;      // 0..15
    const int n0 = tile * BN2;
    const int k0 = chunk * KC2;

    // ---- compute facts for this k-chunk directly into LDS
    #pragma unroll
    for (int i = 0; i < (KC2 * BATCH) / 256; ++i) {
        int idx = i * 256 + tid;
        int k = idx >> 7;                   // 0..95
        int b = idx & 127;
        int kg = k0 + k;
        int d = kg / NTH;
        float z = (x[b * DIM + d] - th[kg]) * sl[kg];
        fs[k * FPITCH + b] = 1.0f / (1.0f + __expf(-z));
    }

    // ---- stage g = e1 - e2 into LDS; per-chunk c (sum e2), S (sum e1+e2)
    const int r = tid >> 3;                 // 0..31 node row
    const int l = tid & 7;                  // 0..7 lane in row
    const int n = n0 + r;
    float cpart = 0.f, spart = 0.f;
    if (n < NODES) {
        const float* row = logits + (size_t)n * (2 * NF) + k0;
        #pragma unroll
        for (int i = 0; i < KC2 / 8; ++i) {
            int k = l + i * 8;
            float e1 = __expf(row[k] * INV_TAU);
            float e2 = __expf(row[k + NF] * INV_TAU);
            gs[r * GPITCH + k] = e1 - e2;
            cpart += e2;
            spart += e1 + e2;
        }
    } else {
        #pragma unroll
        for (int i = 0; i < KC2 / 8; ++i) gs[r * GPITCH + l + i * 8] = 0.f;
    }
    cpart += __shfl_xor(cpart, 1); cpart += __shfl_xor(cpart, 2); cpart += __shfl_xor(cpart, 4);
    spart += __shfl_xor(spart, 1); spart += __shfl_xor(spart, 2); spart += __shfl_xor(spart, 4);
    if (l == 0 && n < NODES) {
        cS[(size_t)chunk * (2 * NPAD) + n] = cpart;
        cS[(size_t)chunk * (2 * NPAD) + NPAD + n] = spart;
    }
    __syncthreads();

    // ---- register-tiled GEMM: acc[b 4][n 4] over this k-chunk
    const int bq = tid & 31;                // 0..31 -> b0 = 4*bq
    const int nq = tid >> 5;                // 0..7  -> node sub-rows nq*4..+3
    const int b0 = bq * 4;
    float acc[4][4] = {};

    #pragma unroll 6
    for (int kk = 0; kk < KC2; kk += 4) {
        float4 f0 = *(const float4*)&fs[(kk + 0) * FPITCH + b0];
        float4 f1 = *(const float4*)&fs[(kk + 1) * FPITCH + b0];
        float4 f2 = *(const float4*)&fs[(kk + 2) * FPITCH + b0];
        float4 f3 = *(const float4*)&fs[(kk + 3) * FPITCH + b0];
        #define STEP(j) { \
            float4 gv = *(const float4*)&gs[(nq * 4 + (j)) * GPITCH + kk]; \
            acc[0][j] += f0.x * gv.x + f1.x * gv.y + f2.x * gv.z + f3.x * gv.w; \
            acc[1][j] += f0.y * gv.x + f1.y * gv.y + f2.y * gv.z + f3.y * gv.w; \
            acc[2][j] += f0.z * gv.x + f1.z * gv.y + f2.z * gv.z + f3.z * gv.w; \
            acc[3][j] += f0.w * gv.x + f1.w * gv.y + f2.w * gv.z + f3.w * gv.w; }
        STEP(0) STEP(1) STEP(2) STEP(3)
        #undef STEP
    }

    // ---- store partial tile (no atomics): partial[chunk][b][n]
    float* pdst = partial + (size_t)chunk * (BATCH * NPAD) + n0 + nq * 4;
    #pragma unroll
    for (int i = 0; i < 4; ++i) {
        float4 st = make_float4(acc[i][0], acc[i][1], acc[i][2], acc[i][3]);
        *(float4*)(pdst + (size_t)(b0 + i) * NPAD) = st;
    }
}

__global__ __launch_bounds__(256) void k_tree(const float* __restrict__ partial,
                                              const float* __restrict__ cS,
                                              const float* __restrict__ LV,
                                              float* __restrict__ out) {
    __shared__ float tl[NPAD];
    __shared__ float Abuf[512 * OD];
    __shared__ float Bbuf[256 * OD];
    const int b = blockIdx.x;
    const int tid = threadIdx.x;

    // each thread handles one float4 group of nodes: n4 = tid*4
    {
        const int n4 = tid * 4;
        float4 s = make_float4(0.f, 0.f, 0.f, 0.f);
        float4 c = make_float4(0.f, 0.f, 0.f, 0.f);
        float4 S = make_float4(0.f, 0.f, 0.f, 0.f);
        #pragma unroll
        for (int ch = 0; ch < KSPLIT; ++ch) {
            float4 p = *(const float4*)&partial[(size_t)ch * (BATCH * NPAD) + (size_t)b * NPAD + n4];
            float4 cc = *(const float4*)&cS[(size_t)ch * (2 * NPAD) + n4];
            float4 SS = *(const float4*)&cS[(size_t)ch * (2 * NPAD) + NPAD + n4];
            s.x += p.x; s.y += p.y; s.z += p.z; s.w += p.w;
            c.x += cc.x; c.y += cc.y; c.z += cc.z; c.w += cc.w;
            S.x += SS.x; S.y += SS.y; S.z += SS.z; S.w += SS.w;
        }
        float4 tv;
        tv.x = fminf(fmaxf((s.x + c.x) / S.x, CLIP_EPS), 1.0f - CLIP_EPS);
        tv.y = fminf(fmaxf((s.y + c.y) / S.y, CLIP_EPS), 1.0f - CLIP_EPS);
        tv.z = fminf(fmaxf((s.z + c.z) / S.z, CLIP_EPS), 1.0f - CLIP_EPS);
        tv.w = fminf(fmaxf((s.w + c.w) / S.w, CLIP_EPS), 1.0f - CLIP_EPS);
        *(float4*)&tl[n4] = tv;   // tl[1023] is garbage but never read
    }
    __syncthreads();

    // depth-9 internal nodes (511..1022): combine leaf_value children
    for (int w = tid; w < 512 * OD; w += 256) {
        int i = w >> 3, o = w & 7;
        float tv = tl[511 + i];
        Abuf[w] = (1.0f - tv) * LV[i * 16 + o] + tv * LV[i * 16 + 8 + o];
    }
    __syncthreads();

    float* cur = Abuf;
    float* nxt = Bbuf;
    for (int lev = 8; lev >= 0; --lev) {
        int cnt = 1 << lev;
        int base = cnt - 1;
        for (int w = tid; w < cnt * OD; w += 256) {
            int i = w >> 3, o = w & 7;
            float tv = tl[base + i];
            nxt[w] = (1.0f - tv) * cur[i * 16 + o] + tv * cur[i * 16 + 8 + o];
        }
        __syncthreads();
        float* tmp = cur; cur = nxt; nxt = tmp;
    }
    if (tid < OD) out[b * OD + tid] = cur[tid];
}

extern "C" void kernel_launch(void* const* d_in, const int* in_sizes, int n_in,
                              void* d_out, int out_size, void* d_ws, size_t ws_size,
                              hipStream_t stream) {
    const float* x      = (const float*)d_in[0];
    const float* th     = (const float*)d_in[1];
    const float* sl     = (const float*)d_in[2];
    const float* logits = (const float*)d_in[3];
    const float* LV     = (const float*)d_in[4];
    float* out = (float*)d_out;
    char* ws = (char*)d_ws;
    float* partial = (float*)(ws + OFF_PART);
    float* cS      = (float*)(ws + OFF_CS);

    k_fused<<<32 * KSPLIT, 256, 0, stream>>>(x, th, sl, logits, partial, cS);
    k_tree<<<BATCH, 256, 0, stream>>>(partial, cS, LV, out);
}

// Round 4
// 20.912 us; speedup vs baseline: 1.6773x; 1.6773x over previous
//
#include <hip/hip_runtime.h>

#define BATCH 128
#define DIM 256
#define NTH 6
#define NF 1536          // NUM_FACTS
#define NODES 1023
#define NPAD 1024
#define OD 8
#define INV_TAU (1.0f/0.7f)
#define CLIP_EPS 1e-6f

// GEMM tiling
#define BN 16            // nodes per tile
#define NTILES 64        // 64 * 16 = 1024 >= 1023
#define KC 192           // k per chunk
#define KSPLIT 8         // 8 * 192 = 1536
#define GP 200           // LDS g pitch in halves (400 B row: 2-way bank alias = free)

typedef _Float16 half_t;
typedef __attribute__((ext_vector_type(8))) _Float16 half8;
typedef __attribute__((ext_vector_type(4))) float f32x4;

// ws layout (bytes)
#define OFF_PART 0                         // partial [KSPLIT][BATCH][NPAD] f32 = 4 MiB
#define OFF_CS   (4*1024*1024)             // cS [KSPLIT][2][NPAD] f32 = 64 KiB
#define OFF_FT   (4*1024*1024 + 65536)     // fT [BATCH][NF] f16 = 384 KiB

__global__ __launch_bounds__(256) void k_facts(const float* __restrict__ x,
                                               const float* __restrict__ th,
                                               const float* __restrict__ sl,
                                               half_t* __restrict__ fT) {
    const int b = blockIdx.y;
    const int kk = blockIdx.x * 256 + threadIdx.x;   // 0..767 (pair index)
    const int k = kk * 2;
    const int d = k / NTH;                            // pair never crosses a d boundary
    float xv = x[b * DIM + d];
    float2 t2 = *(const float2*)&th[k];
    float2 s2 = *(const float2*)&sl[k];
    float f0 = 1.0f / (1.0f + __expf(-(xv - t2.x) * s2.x));
    float f1 = 1.0f / (1.0f + __expf(-(xv - t2.y) * s2.y));
    union { half_t h[2]; unsigned int u; } p;
    p.h[0] = (half_t)f0; p.h[1] = (half_t)f1;
    *(unsigned int*)&fT[(size_t)b * NF + k] = p.u;
}

__global__ __launch_bounds__(256) void k_gemm(const float* __restrict__ logits,
                                              const half_t* __restrict__ fT,
                                              float* __restrict__ partial,
                                              float* __restrict__ cS) {
    __shared__ __align__(16) half_t gs[BN * GP];
    const int tid = threadIdx.x;
    const int tile = blockIdx.x >> 3;       // 0..63
    const int chunk = blockIdx.x & 7;       // 0..7
    const int n0 = tile * BN;
    const int k0 = chunk * KC;

    // ---- stage g = e1 - e2 (fp16) into LDS; per-chunk c = sum e2, S = sum(e1+e2)
    const int r = tid >> 4;                 // 0..15 node row
    const int j = tid & 15;                 // 0..15 lane in row
    const int n = n0 + r;
    float cpart = 0.f, spart = 0.f;
    if (n < NODES) {
        const float* row = logits + (size_t)n * (2 * NF) + k0;
        #pragma unroll
        for (int i = 0; i < 6; ++i) {
            int kp = j * 2 + 32 * i;
            float2 a1 = *(const float2*)&row[kp];
            float2 a2 = *(const float2*)&row[kp + NF];
            float e10 = __expf(a1.x * INV_TAU), e11 = __expf(a1.y * INV_TAU);
            float e20 = __expf(a2.x * INV_TAU), e21 = __expf(a2.y * INV_TAU);
            union { half_t h[2]; unsigned int u; } p;
            p.h[0] = (half_t)(e10 - e20); p.h[1] = (half_t)(e11 - e21);
            *(unsigned int*)&gs[r * GP + kp] = p.u;
            cpart += e20 + e21;
            spart += e10 + e11 + e20 + e21;
        }
    } else {
        #pragma unroll
        for (int i = 0; i < 6; ++i)
            *(unsigned int*)&gs[r * GP + j * 2 + 32 * i] = 0u;
    }
    cpart += __shfl_xor(cpart, 1); cpart += __shfl_xor(cpart, 2);
    cpart += __shfl_xor(cpart, 4); cpart += __shfl_xor(cpart, 8);
    spart += __shfl_xor(spart, 1); spart += __shfl_xor(spart, 2);
    spart += __shfl_xor(spart, 4); spart += __shfl_xor(spart, 8);
    if (j == 0 && n < NODES) {
        cS[(size_t)chunk * (2 * NPAD) + n] = cpart;
        cS[(size_t)chunk * (2 * NPAD) + NPAD + n] = spart;
    }
    __syncthreads();

    // ---- MFMA: out[n 16][b 128]; 4 waves x 2 b-tiles of 16
    const int wave = tid >> 6;
    const int lane = tid & 63;
    const int bcol = lane & 15;             // B col = batch
    const int kq = lane >> 4;               // 0..3 (k-quad)
    const int b0 = wave * 32;
    f32x4 acc0 = {0.f, 0.f, 0.f, 0.f};
    f32x4 acc1 = {0.f, 0.f, 0.f, 0.f};
    const half_t* fb0 = fT + (size_t)(b0 + bcol) * NF + k0 + kq * 8;
    const half_t* fb1 = fb0 + (size_t)16 * NF;
    const half_t* ga = gs + bcol * GP + kq * 8;   // A row = lane&15

    #pragma unroll
    for (int s = 0; s < 6; ++s) {
        half8 av  = *(const half8*)(ga  + s * 32);
        half8 bv0 = *(const half8*)(fb0 + s * 32);
        half8 bv1 = *(const half8*)(fb1 + s * 32);
        acc0 = __builtin_amdgcn_mfma_f32_16x16x32_f16(av, bv0, acc0, 0, 0, 0);
        acc1 = __builtin_amdgcn_mfma_f32_16x16x32_f16(av, bv1, acc1, 0, 0, 0);
    }

    // D layout: col(b) = lane&15, row(n) = (lane>>4)*4 + reg -> 4 consecutive n = float4
    float* p0 = partial + (size_t)chunk * (BATCH * NPAD) + (size_t)(b0 + bcol) * NPAD + n0 + kq * 4;
    *(f32x4*)p0 = acc0;
    *(f32x4*)(p0 + (size_t)16 * NPAD) = acc1;
}

__global__ __launch_bounds__(256) void k_tree(const float* __restrict__ partial,
                                              const float* __restrict__ cS,
                                              const float* __restrict__ LV,
                                              float* __restrict__ out) {
    __shared__ float tl[NPAD];
    __shared__ float Abuf[512 * OD];
    __shared__ float Bbuf[256 * OD];
    const int b = blockIdx.x;
    const int tid = threadIdx.x;

    {
        const int n4 = tid * 4;
        float4 s = make_float4(0.f, 0.f, 0.f, 0.f);
        float4 c = make_float4(0.f, 0.f, 0.f, 0.f);
        float4 S = make_float4(0.f, 0.f, 0.f, 0.f);
        #pragma unroll
        for (int ch = 0; ch < KSPLIT; ++ch) {
            float4 p = *(const float4*)&partial[(size_t)ch * (BATCH * NPAD) + (size_t)b * NPAD + n4];
            float4 cc = *(const float4*)&cS[(size_t)ch * (2 * NPAD) + n4];
            float4 SS = *(const float4*)&cS[(size_t)ch * (2 * NPAD) + NPAD + n4];
            s.x += p.x; s.y += p.y; s.z += p.z; s.w += p.w;
            c.x += cc.x; c.y += cc.y; c.z += cc.z; c.w += cc.w;
            S.x += SS.x; S.y += SS.y; S.z += SS.z; S.w += SS.w;
        }
        float4 tv;
        tv.x = fminf(fmaxf((s.x + c.x) / S.x, CLIP_EPS), 1.0f - CLIP_EPS);
        tv.y = fminf(fmaxf((s.y + c.y) / S.y, CLIP_EPS), 1.0f - CLIP_EPS);
        tv.z = fminf(fmaxf((s.z + c.z) / S.z, CLIP_EPS), 1.0f - CLIP_EPS);
        tv.w = fminf(fmaxf((s.w + c.w) / S.w, CLIP_EPS), 1.0f - CLIP_EPS);
        *(float4*)&tl[n4] = tv;   // tl[1023] garbage but never read
    }
    __syncthreads();

    // depth-9 internal nodes (511..1022): combine leaf_value children
    for (int w = tid; w < 512 * OD; w += 256) {
        int i = w >> 3, o = w & 7;
        float tv = tl[511 + i];
        Abuf[w] = (1.0f - tv) * LV[i * 16 + o] + tv * LV[i * 16 + 8 + o];
    }
    __syncthreads();

    float* cur = Abuf;
    float* nxt = Bbuf;
    for (int lev = 8; lev >= 0; --lev) {
        int cnt = 1 << lev;
        int base = cnt - 1;
        for (int w = tid; w < cnt * OD; w += 256) {
            int i = w >> 3, o = w & 7;
            float tv = tl[base + i];
            nxt[w] = (1.0f - tv) * cur[i * 16 + o] + tv * cur[i * 16 + 8 + o];
        }
        __syncthreads();
        float* tmp = cur; cur = nxt; nxt = tmp;
    }
    if (tid < OD) out[b * OD + tid] = cur[tid];
}

extern "C" void kernel_launch(void* const* d_in, const int* in_sizes, int n_in,
                              void* d_out, int out_size, void* d_ws, size_t ws_size,
                              hipStream_t stream) {
    const float* x      = (const float*)d_in[0];
    const float* th     = (const float*)d_in[1];
    const float* sl     = (const float*)d_in[2];
    const float* logits = (const float*)d_in[3];
    const float* LV     = (const float*)d_in[4];
    float* out = (float*)d_out;
    char* ws = (char*)d_ws;
    float* partial = (float*)(ws + OFF_PART);
    float* cS      = (float*)(ws + OFF_CS);
    half_t* fT     = (half_t*)(ws + OFF_FT);

    k_facts<<<dim3(3, BATCH), 256, 0, stream>>>(x, th, sl, fT);
    k_gemm<<<NTILES * KSPLIT, 256, 0, stream>>>(logits, fT, partial, cS);
    k_tree<<<BATCH, 256, 0, stream>>>(partial, cS, LV, out);
}